// Round 2
// baseline (20354.315 us; speedup 1.0000x reference)
//
#include <hip/hip_runtime.h>

// LSTM: T=16384 steps, B=32 batches, H=96 hidden, gates 4H=384.
// One workgroup per batch (32 blocks, 1 CU each); 384 threads = 6 waves.
// Thread g owns row g of w_hh, PINNED in 96 VGPRs via asm (round 1 showed the
// compiler sinking the loads into the loop -> 147KB/step L2 reads, 2100cyc/step).
// h broadcast via LDS (uniform-address ds_read = free broadcast).
// 4 parallel accumulators break the 96-deep FMA dependency chain.

constexpr int HH = 96;     // hidden
constexpr int GG = 384;    // 4*H gates
constexpr int BB = 32;     // batch
constexpr int TT = 16384;  // timesteps
constexpr int CH = 2048;   // x chunk in LDS (8 KB)

__launch_bounds__(GG, 1)
__global__ void lstm_kernel(const float* __restrict__ x,
                            const float* __restrict__ w_ih,
                            const float* __restrict__ w_hh,
                            const float* __restrict__ b_ih,
                            const float* __restrict__ b_hh,
                            const float* __restrict__ fc_w,
                            const float* __restrict__ fc_b,
                            float* __restrict__ out) {
    __shared__ float xs[CH];
    __shared__ float act_s[GG];
    __shared__ float h_s[HH];
    __shared__ float red_s[2];

    const int g = threadIdx.x;   // gate row 0..383
    const int b = blockIdx.x;    // batch 0..31

    // One-time load of this thread's w_hh row; pin in VGPRs so the compiler
    // cannot rematerialize the global loads inside the time loop.
    float W[HH];
    {
        const float4* wrow = reinterpret_cast<const float4*>(w_hh + g * HH);
#pragma unroll
        for (int kk = 0; kk < 24; ++kk) {
            float4 v = wrow[kk];
            W[4 * kk + 0] = v.x;
            W[4 * kk + 1] = v.y;
            W[4 * kk + 2] = v.z;
            W[4 * kk + 3] = v.w;
        }
    }
#pragma unroll
    for (int i = 0; i < HH; ++i) asm volatile("" : "+v"(W[i]));

    const float wih_g  = w_ih[g];
    const float bias_g = b_ih[g] + b_hh[g];

    // Branchless activation: sigmoid(x)=1/(1+e^-x); tanh(x)=2/(1+e^-2x)-1.
    // gates order: i[0:96) f[96:192) g[192:288) o[288:384)
    const bool is_tanh = (g >= 2 * HH && g < 3 * HH);
    const float a_scale = is_tanh ? 2.0f : 1.0f;
    const float a_mul   = is_tanh ? 2.0f : 1.0f;
    const float a_add   = is_tanh ? -1.0f : 0.0f;

    float c = 0.0f;
    const float fcw_j = (g < HH) ? fc_w[g] : 0.0f;
    const float fcb   = fc_b[0];

    if (g < HH) h_s[g] = 0.0f;
    float x_prev = 0.0f;
    __syncthreads();

    for (int t = 0; t < TT; ++t) {
        // Refill x chunk every CH steps (readers of old chunk are past bar2).
        if ((t & (CH - 1)) == 0) {
            for (int i = g; i < CH; i += GG) xs[i] = x[(t + i) * BB + b];
            __syncthreads();
        }
        const float xv = xs[t & (CH - 1)];

        // Deferred output store for step t-1 (red_s valid: written before bar2,
        // next overwrite only after bar1 of this step).
        if (g == 128) {
            if (t > 0) out[(t - 1) * BB + b] = red_s[0] + red_s[1] + fcb + x_prev;
            x_prev = xv;
        }

        // ---- Phase A: gate matvec (reads h_s, writes act_s) ----
        // 4 parallel accumulator chains (24 deep each) instead of 1x96.
        float acc0 = fmaf(xv, wih_g, bias_g);
        float acc1 = 0.0f, acc2 = 0.0f, acc3 = 0.0f;
        const float4* h4 = reinterpret_cast<const float4*>(h_s);
#pragma unroll
        for (int kk = 0; kk < 24; ++kk) {
            const float4 hv = h4[kk];   // uniform address -> LDS broadcast
            acc0 = fmaf(W[4 * kk + 0], hv.x, acc0);
            acc1 = fmaf(W[4 * kk + 1], hv.y, acc1);
            acc2 = fmaf(W[4 * kk + 2], hv.z, acc2);
            acc3 = fmaf(W[4 * kk + 3], hv.w, acc3);
        }
        const float acc = (acc0 + acc1) + (acc2 + acc3);
        const float s = __builtin_amdgcn_rcpf(1.0f + __expf(-acc * a_scale));
        act_s[g] = fmaf(s, a_mul, a_add);
        __syncthreads();   // bar1: act_s ready

        // ---- Phase B: c/h update + output partial reduce (waves 0,1) ----
        if (g < 128) {
            float p = 0.0f;
            if (g < HH) {
                const float iv = act_s[g];
                const float fv = act_s[HH + g];
                const float gv = act_s[2 * HH + g];
                const float ov = act_s[3 * HH + g];
                c = fmaf(fv, c, iv * gv);
                const float th =
                    fmaf(2.0f, __builtin_amdgcn_rcpf(1.0f + __expf(-2.0f * c)), -1.0f);
                const float h = ov * th;
                h_s[g] = h;
                p = h * fcw_j;
            }
#pragma unroll
            for (int off = 32; off > 0; off >>= 1) p += __shfl_down(p, off);
            if ((g & 63) == 0) red_s[g >> 6] = p;
        }
        __syncthreads();   // bar2: h_s + red_s ready
    }
    // Final deferred store (red_s for t = TT-1 is valid after last bar2).
    if (g == 128) out[(TT - 1) * BB + b] = red_s[0] + red_s[1] + fcb + x_prev;
}

extern "C" void kernel_launch(void* const* d_in, const int* in_sizes, int n_in,
                              void* d_out, int out_size, void* d_ws, size_t ws_size,
                              hipStream_t stream) {
    const float* x    = (const float*)d_in[0];
    const float* w_ih = (const float*)d_in[1];
    const float* w_hh = (const float*)d_in[2];
    const float* b_ih = (const float*)d_in[3];
    const float* b_hh = (const float*)d_in[4];
    const float* fc_w = (const float*)d_in[5];
    const float* fc_b = (const float*)d_in[6];
    float* out = (float*)d_out;

    lstm_kernel<<<dim3(BB), dim3(GG), 0, stream>>>(x, w_ih, w_hh, b_ih, b_hh,
                                                   fc_w, fc_b, out);
}

// Round 3
// 12669.391 us; speedup vs baseline: 1.6066x; 1.6066x over previous
//
#include <hip/hip_runtime.h>

// LSTM: T=16384, B=32, H=96, gates 4H=384. One block per batch (32 blocks).
// R2 lesson: 96 weights/thread spills (VGPR=88 + scratch). Split each gate row
// across an even/odd lane PAIR: 768 threads (12 waves, 3/SIMD), 48 weights each
// (~85 VGPR, fits). Partial dots combined with intra-wave __shfl_xor(acc,1).
// h broadcast via LDS; 2 barriers/step; output reduce deferred one step.

constexpr int HH = 96;     // hidden
constexpr int GG = 384;    // 4*H gate rows
constexpr int TH = 768;    // threads = 2 per gate row
constexpr int BB = 32;     // batch
constexpr int TT = 16384;  // timesteps
constexpr int CH = 2048;   // x chunk in LDS (8 KB)

__launch_bounds__(TH, 1)
__global__ void lstm_kernel(const float* __restrict__ x,
                            const float* __restrict__ w_ih,
                            const float* __restrict__ w_hh,
                            const float* __restrict__ b_ih,
                            const float* __restrict__ b_hh,
                            const float* __restrict__ fc_w,
                            const float* __restrict__ fc_b,
                            float* __restrict__ out) {
    __shared__ float xs[CH];
    __shared__ float act_s[GG];
    __shared__ float h_s[HH];
    __shared__ float red_s[2];

    const int tid  = threadIdx.x;    // 0..767
    const int row  = tid >> 1;       // gate row 0..383
    const int half = tid & 1;        // which 48-wide half of the row
    const int b    = blockIdx.x;     // batch 0..31

    // One-time load: 48 weights (half a w_hh row). 12 float4s, pinned so the
    // compiler can't sink the loads into the time loop.
    float W[48];
    {
        const float4* wrow =
            reinterpret_cast<const float4*>(w_hh + row * HH + half * 48);
#pragma unroll
        for (int kk = 0; kk < 12; ++kk) {
            float4 v = wrow[kk];
            W[4 * kk + 0] = v.x;
            W[4 * kk + 1] = v.y;
            W[4 * kk + 2] = v.z;
            W[4 * kk + 3] = v.w;
        }
    }
#pragma unroll
    for (int i = 0; i < 48; ++i) asm volatile("" : "+v"(W[i]));

    const bool half0  = (half == 0);
    const float wih_g  = half0 ? w_ih[row] : 0.0f;
    const float bias_g = half0 ? (b_ih[row] + b_hh[row]) : 0.0f;

    // Branchless activation: sigmoid(v)=1/(1+e^-v); tanh(v)=2/(1+e^-2v)-1.
    // Row order: i[0:96) f[96:192) g[192:288) o[288:384)
    const bool is_tanh = (row >= 2 * HH && row < 3 * HH);
    const float a_scale = is_tanh ? 2.0f : 1.0f;
    const float a_mul   = is_tanh ? 2.0f : 1.0f;
    const float a_add   = is_tanh ? -1.0f : 0.0f;

    float c = 0.0f;                                  // cell state (tid<96)
    const float fcw_j = (tid < HH) ? fc_w[tid] : 0.0f;
    const float fcb   = fc_b[0];

    if (tid < HH) h_s[tid] = 0.0f;
    float x_prev = 0.0f;
    __syncthreads();

    for (int t = 0; t < TT; ++t) {
        // Refill x chunk every CH steps (old-chunk readers are past bar2).
        if ((t & (CH - 1)) == 0) {
            for (int i = tid; i < CH; i += TH) xs[i] = x[(t + i) * BB + b];
            __syncthreads();
        }
        const float xv = xs[t & (CH - 1)];

        // Deferred output store for step t-1 (wave 2; red_s written before the
        // previous bar2, next overwritten only after this step's bar1).
        if (tid == 128) {
            if (t > 0) out[(t - 1) * BB + b] = red_s[0] + red_s[1] + fcb + x_prev;
            x_prev = xv;
        }

        // ---- Phase A: half-row matvec (reads h_s, writes act_s) ----
        float a0 = half0 ? fmaf(xv, wih_g, bias_g) : 0.0f;
        float a1 = 0.0f, a2 = 0.0f, a3 = 0.0f;
        const float4* h4 = reinterpret_cast<const float4*>(h_s) + half * 12;
#pragma unroll
        for (int kk = 0; kk < 12; ++kk) {
            const float4 hv = h4[kk];   // 2 distinct addrs/wave -> broadcast
            a0 = fmaf(W[4 * kk + 0], hv.x, a0);
            a1 = fmaf(W[4 * kk + 1], hv.y, a1);
            a2 = fmaf(W[4 * kk + 2], hv.z, a2);
            a3 = fmaf(W[4 * kk + 3], hv.w, a3);
        }
        float acc = (a0 + a1) + (a2 + a3);
        acc += __shfl_xor(acc, 1);      // even/odd lanes combine halves
        if (half0) {
            const float s = __builtin_amdgcn_rcpf(1.0f + __expf(-acc * a_scale));
            act_s[row] = fmaf(s, a_mul, a_add);
        }
        __syncthreads();   // bar1: act_s ready

        // ---- Phase B: c/h update + output partial reduce (waves 0,1) ----
        if (tid < 128) {
            float p = 0.0f;
            if (tid < HH) {
                const float iv = act_s[tid];
                const float fv = act_s[HH + tid];
                const float gv = act_s[2 * HH + tid];
                const float ov = act_s[3 * HH + tid];
                c = fmaf(fv, c, iv * gv);
                const float th =
                    fmaf(2.0f, __builtin_amdgcn_rcpf(1.0f + __expf(-2.0f * c)), -1.0f);
                const float h = ov * th;
                h_s[tid] = h;
                p = h * fcw_j;
            }
#pragma unroll
            for (int off = 32; off > 0; off >>= 1) p += __shfl_down(p, off);
            if ((tid & 63) == 0) red_s[tid >> 6] = p;
        }
        __syncthreads();   // bar2: h_s + red_s ready
    }
    // Final deferred store (red_s for t = TT-1 valid after last bar2).
    if (tid == 128) out[(TT - 1) * BB + b] = red_s[0] + red_s[1] + fcb + x_prev;
}

extern "C" void kernel_launch(void* const* d_in, const int* in_sizes, int n_in,
                              void* d_out, int out_size, void* d_ws, size_t ws_size,
                              hipStream_t stream) {
    const float* x    = (const float*)d_in[0];
    const float* w_ih = (const float*)d_in[1];
    const float* w_hh = (const float*)d_in[2];
    const float* b_ih = (const float*)d_in[3];
    const float* b_hh = (const float*)d_in[4];
    const float* fc_w = (const float*)d_in[5];
    const float* fc_b = (const float*)d_in[6];
    float* out = (float*)d_out;

    lstm_kernel<<<dim3(BB), dim3(TH), 0, stream>>>(x, w_ih, w_hh, b_ih, b_hh,
                                                   fc_w, fc_b, out);
}

// Round 4
// 12531.496 us; speedup vs baseline: 1.6243x; 1.0110x over previous
//
#include <hip/hip_runtime.h>

// LSTM: T=16384, B=32, H=96, gates 4H=384. One block per batch (32 blocks).
// R1-R3 lesson: the allocator was working to the DEFAULT waves-per-EU max
// (~10), capping VGPR budget near 51 -> weights spilled to scratch -> every
// step re-read 147KB/block from L2 (~1900-2300 cyc/step). Fix: pin occupancy
// with amdgpu_waves_per_eu(1,3) so the budget is 512/3 ~= 170 VGPRs and the
// 48 weights/thread stay register-resident.
// Structure: 768 threads (12 waves, 3/SIMD); even/odd lane pair owns one gate
// row (48 weights each); partial dots combined via __shfl_xor(acc,1);
// h broadcast via LDS; 2 barriers/step; output projection deferred one step.

constexpr int HH = 96;     // hidden
constexpr int GG = 384;    // 4*H gate rows
constexpr int TH = 768;    // threads = 2 per gate row
constexpr int BB = 32;     // batch
constexpr int TT = 16384;  // timesteps
constexpr int CH = 2048;   // x chunk in LDS (8 KB)

__attribute__((amdgpu_flat_work_group_size(TH, TH), amdgpu_waves_per_eu(1, 3)))
__global__ void lstm_kernel(const float* __restrict__ x,
                            const float* __restrict__ w_ih,
                            const float* __restrict__ w_hh,
                            const float* __restrict__ b_ih,
                            const float* __restrict__ b_hh,
                            const float* __restrict__ fc_w,
                            const float* __restrict__ fc_b,
                            float* __restrict__ out) {
    __shared__ float xs[CH];
    __shared__ float act_s[GG];
    __shared__ float h_s[HH];
    __shared__ float red_s[2];

    const int tid  = threadIdx.x;    // 0..767
    const int row  = tid >> 1;       // gate row 0..383
    const int half = tid & 1;        // which 48-wide half of the row
    const int b    = blockIdx.x;     // batch 0..31

    // One-time load: 48 weights (half a w_hh row), pinned so the loads can't
    // be sunk into the time loop.
    float W[48];
    {
        const float4* wrow =
            reinterpret_cast<const float4*>(w_hh + row * HH + half * 48);
#pragma unroll
        for (int kk = 0; kk < 12; ++kk) {
            float4 v = wrow[kk];
            W[4 * kk + 0] = v.x;
            W[4 * kk + 1] = v.y;
            W[4 * kk + 2] = v.z;
            W[4 * kk + 3] = v.w;
        }
    }
#pragma unroll
    for (int i = 0; i < 48; ++i) asm volatile("" : "+v"(W[i]));

    const bool half0  = (half == 0);
    const float wih_g  = half0 ? w_ih[row] : 0.0f;
    const float bias_g = half0 ? (b_ih[row] + b_hh[row]) : 0.0f;

    // Branchless activation: sigmoid(v)=1/(1+e^-v); tanh(v)=2/(1+e^-2v)-1.
    // Row order: i[0:96) f[96:192) g[192:288) o[288:384)
    const bool is_tanh = (row >= 2 * HH && row < 3 * HH);
    const float a_scale = is_tanh ? 2.0f : 1.0f;
    const float a_mul   = is_tanh ? 2.0f : 1.0f;
    const float a_add   = is_tanh ? -1.0f : 0.0f;

    float c = 0.0f;                                  // cell state (tid<96)
    const float fcw_j = (tid < HH) ? fc_w[tid] : 0.0f;
    const float fcb   = fc_b[0];

    if (tid < HH) h_s[tid] = 0.0f;
    float x_prev = 0.0f;
    __syncthreads();

    for (int t = 0; t < TT; ++t) {
        // Refill x chunk every CH steps (old-chunk readers are past bar2).
        if ((t & (CH - 1)) == 0) {
            for (int i = tid; i < CH; i += TH) xs[i] = x[(t + i) * BB + b];
            __syncthreads();
        }
        const float xv = xs[t & (CH - 1)];

        // Deferred output store for step t-1 (wave 2; red_s written before the
        // previous bar2, next overwritten only after this step's bar1).
        if (tid == 128) {
            if (t > 0) out[(t - 1) * BB + b] = red_s[0] + red_s[1] + fcb + x_prev;
            x_prev = xv;
        }

        // ---- Phase A: half-row matvec (reads h_s, writes act_s) ----
        float a0 = half0 ? fmaf(xv, wih_g, bias_g) : 0.0f;
        float a1 = 0.0f, a2 = 0.0f, a3 = 0.0f;
        const float4* h4 = reinterpret_cast<const float4*>(h_s) + half * 12;
#pragma unroll
        for (int kk = 0; kk < 12; ++kk) {
            const float4 hv = h4[kk];   // 2 distinct addrs/wave -> broadcast
            a0 = fmaf(W[4 * kk + 0], hv.x, a0);
            a1 = fmaf(W[4 * kk + 1], hv.y, a1);
            a2 = fmaf(W[4 * kk + 2], hv.z, a2);
            a3 = fmaf(W[4 * kk + 3], hv.w, a3);
        }
        float acc = (a0 + a1) + (a2 + a3);
        acc += __shfl_xor(acc, 1);      // even/odd lanes combine halves
        if (half0) {
            const float s = __builtin_amdgcn_rcpf(1.0f + __expf(-acc * a_scale));
            act_s[row] = fmaf(s, a_mul, a_add);
        }
        __syncthreads();   // bar1: act_s ready

        // ---- Phase B: c/h update + output partial reduce (waves 0,1) ----
        if (tid < 128) {
            float p = 0.0f;
            if (tid < HH) {
                const float iv = act_s[tid];
                const float fv = act_s[HH + tid];
                const float gv = act_s[2 * HH + tid];
                const float ov = act_s[3 * HH + tid];
                c = fmaf(fv, c, iv * gv);
                const float th =
                    fmaf(2.0f, __builtin_amdgcn_rcpf(1.0f + __expf(-2.0f * c)), -1.0f);
                const float h = ov * th;
                h_s[tid] = h;
                p = h * fcw_j;
            }
#pragma unroll
            for (int off = 32; off > 0; off >>= 1) p += __shfl_down(p, off);
            if ((tid & 63) == 0) red_s[tid >> 6] = p;
        }
        __syncthreads();   // bar2: h_s + red_s ready
    }
    // Final deferred store (red_s for t = TT-1 valid after last bar2).
    if (tid == 128) out[(TT - 1) * BB + b] = red_s[0] + red_s[1] + fcb + x_prev;
}

extern "C" void kernel_launch(void* const* d_in, const int* in_sizes, int n_in,
                              void* d_out, int out_size, void* d_ws, size_t ws_size,
                              hipStream_t stream) {
    const float* x    = (const float*)d_in[0];
    const float* w_ih = (const float*)d_in[1];
    const float* w_hh = (const float*)d_in[2];
    const float* b_ih = (const float*)d_in[3];
    const float* b_hh = (const float*)d_in[4];
    const float* fc_w = (const float*)d_in[5];
    const float* fc_b = (const float*)d_in[6];
    float* out = (float*)d_out;

    lstm_kernel<<<dim3(BB), dim3(TH), 0, stream>>>(x, w_ih, w_hh, b_ih, b_hh,
                                                   fc_w, fc_b, out);
}